// Round 1
// baseline (167.261 us; speedup 1.0000x reference)
//
#include <hip/hip_runtime.h>

#define IGNORE_INDEX (-100)
#define C_DIM 32

struct Ctrl {
    unsigned hist[4][256];   // one histogram per radix pass
    unsigned pos_num;
    unsigned prefix;         // selected high bits of threshold dkey
    unsigned rank;           // remaining 0-based rank within current prefix
    unsigned use_thr;        // 1 if num_neg > neg_sum (threshold branch)
    unsigned cnt;            // valid count
    unsigned pad;
    double   sum;            // nll sum
};

__global__ void init_kernel(unsigned* c, int words) {
    for (int i = threadIdx.x + blockIdx.x * blockDim.x; i < words;
         i += blockDim.x * gridDim.x)
        c[i] = 0u;
}

// Wave-aggregated LDS histogram add: the top-byte distribution has only a
// handful of distinct values (exponent bytes of maxima + the -inf bucket),
// so naive per-lane atomicAdd would serialize 64-way. Aggregate per distinct
// value within the wave instead (~5 iterations expected).
__device__ inline void wave_hist_add(unsigned* h, unsigned bucket) {
    unsigned long long todo = __ballot(1);
    while (todo) {
        int leader = (int)__builtin_ctzll(todo);
        unsigned b = __shfl(bucket, leader);
        unsigned long long same = __ballot(bucket == b) & todo;
        if ((int)(threadIdx.x & 63) == leader)
            atomicAdd(&h[b], (unsigned)__popcll(same));
        todo &= ~same;
    }
}

__global__ void __launch_bounds__(256)
row_kernel(const float* __restrict__ pred, const int* __restrict__ label,
           unsigned* __restrict__ keys, float* __restrict__ nll,
           Ctrl* __restrict__ c, int n) {
    __shared__ unsigned h[256];
    for (int i = threadIdx.x; i < 256; i += 256) h[i] = 0u;
    __syncthreads();

    int pos_local = 0;
    const int stride = gridDim.x * blockDim.x;
    for (int row = blockIdx.x * blockDim.x + threadIdx.x; row < n; row += stride) {
        const float4* p = reinterpret_cast<const float4*>(pred) + (size_t)row * 8;
        float r[32];
#pragma unroll
        for (int j = 0; j < 8; ++j) {
            float4 v = p[j];
            r[4 * j + 0] = v.x; r[4 * j + 1] = v.y;
            r[4 * j + 2] = v.z; r[4 * j + 3] = v.w;
        }
        // max over non-background columns 1..31
        float m_nb = r[1];
#pragma unroll
        for (int j = 2; j < 32; ++j) m_nb = fmaxf(m_nb, r[j]);
        float m_all = fmaxf(m_nb, r[0]);

        float s = 0.f;
#pragma unroll
        for (int j = 0; j < 32; ++j) s += __expf(r[j] - m_all);

        int lab = label[row];
        int sl = lab; if (sl < 0) sl = 0; if (sl > 31) sl = 31;
        float xl = r[0];
#pragma unroll
        for (int j = 1; j < 32; ++j) xl = (j == sl) ? r[j] : xl;

        nll[row] = (m_all + __logf(s)) - xl;

        bool is_pos = (lab != 0);
        pos_local += is_pos ? 1 : 0;

        float ns = is_pos ? -__builtin_inff() : m_nb;
        unsigned u = __float_as_uint(ns);
        unsigned ukey = (u & 0x80000000u) ? ~u : (u | 0x80000000u); // ascending float order
        unsigned dkey = ~ukey;                                      // ascending = descending float
        keys[row] = dkey;
        wave_hist_add(h, dkey >> 24);
    }

    // block-reduce positive count
#pragma unroll
    for (int off = 32; off > 0; off >>= 1) pos_local += __shfl_down(pos_local, off);
    __shared__ int wsum[4];
    int wid = threadIdx.x >> 6, lane = threadIdx.x & 63;
    if (lane == 0) wsum[wid] = pos_local;
    __syncthreads();
    if (threadIdx.x == 0)
        atomicAdd(&c->pos_num, (unsigned)(wsum[0] + wsum[1] + wsum[2] + wsum[3]));

    for (int i = threadIdx.x; i < 256; i += 256)
        if (h[i]) atomicAdd(&c->hist[3][i], h[i]);
}

__global__ void __launch_bounds__(256)
hist_kernel(const unsigned* __restrict__ keys, Ctrl* __restrict__ c, int n, int pass) {
    __shared__ unsigned h[256];
    for (int i = threadIdx.x; i < 256; i += 256) h[i] = 0u;
    __syncthreads();
    const unsigned prefix = c->prefix;
    const unsigned pmask = 0xFFFFFFFFu << (8 * (pass + 1));
    const int shift = 8 * pass;
    const int stride = gridDim.x * blockDim.x;
    for (int i = blockIdx.x * blockDim.x + threadIdx.x; i < n; i += stride) {
        unsigned k = keys[i];
        if ((k & pmask) == prefix) atomicAdd(&h[(k >> shift) & 0xFFu], 1u);
    }
    __syncthreads();
    for (int i = threadIdx.x; i < 256; i += 256)
        if (h[i]) atomicAdd(&c->hist[pass][i], h[i]);
}

__global__ void scan_kernel(Ctrl* __restrict__ c, const int* __restrict__ factor_p,
                            int pass, int n) {
    __shared__ unsigned s[256];
    __shared__ unsigned sh_rank;
    int t = threadIdx.x;
    if (t == 0) {
        if (pass == 3) {
            long long pos = (long long)c->pos_num;
            long long fac = (long long)factor_p[0];
            long long neg_sum = pos * fac;
            long long num_neg = (long long)n - pos;
            long long idx = neg_sum - 1;
            if (idx < 0) idx = 0;
            if (idx > (long long)n - 1) idx = (long long)n - 1;
            sh_rank = (unsigned)idx;
            c->use_thr = (num_neg > neg_sum) ? 1u : 0u;
        } else {
            sh_rank = c->rank;
        }
    }
    __syncthreads();
    unsigned cnt = c->hist[pass][t];
    s[t] = cnt;
    __syncthreads();
#pragma unroll
    for (int off = 1; off < 256; off <<= 1) {
        unsigned v = (t >= off) ? s[t - off] : 0u;
        __syncthreads();
        s[t] += v;
        __syncthreads();
    }
    unsigned rank = sh_rank;
    unsigned incl = s[t];
    unsigned excl = incl - cnt;
    if (cnt > 0u && excl <= rank && rank < incl) {
        c->prefix |= ((unsigned)t) << (8 * pass);
        c->rank = rank - excl;
    }
}

__global__ void __launch_bounds__(256)
reduce_kernel(const unsigned* __restrict__ keys, const int* __restrict__ label,
              const float* __restrict__ nll, Ctrl* __restrict__ c, int n) {
    const bool use_thr = (c->use_thr != 0u);
    const unsigned thr = c->prefix;
    double local = 0.0;
    int cntl = 0;
    const int stride = gridDim.x * blockDim.x;
    for (int i = blockIdx.x * blockDim.x + threadIdx.x; i < n; i += stride) {
        int lab = label[i];
        bool mask = use_thr ? ((lab != 0) || (keys[i] <= thr)) : (lab != -1);
        if (mask) { local += (double)nll[i]; cntl++; }
    }
#pragma unroll
    for (int off = 32; off > 0; off >>= 1) {
        local += __shfl_down(local, off);
        cntl  += __shfl_down(cntl, off);
    }
    __shared__ double sd[4];
    __shared__ int    si[4];
    int wid = threadIdx.x >> 6, lane = threadIdx.x & 63;
    if (lane == 0) { sd[wid] = local; si[wid] = cntl; }
    __syncthreads();
    if (threadIdx.x == 0) {
        double tot = sd[0] + sd[1] + sd[2] + sd[3];
        int ct = si[0] + si[1] + si[2] + si[3];
        atomicAdd(&c->sum, tot);
        atomicAdd(&c->cnt, (unsigned)ct);
    }
}

__global__ void final_kernel(const Ctrl* __restrict__ c, float* __restrict__ out) {
    if (threadIdx.x == 0 && blockIdx.x == 0) {
        unsigned ct = c->cnt;
        double denom = (ct == 0u) ? 1.0 : (double)ct;
        out[0] = (float)(c->sum / denom);
    }
}

extern "C" void kernel_launch(void* const* d_in, const int* in_sizes, int n_in,
                              void* d_out, int out_size, void* d_ws, size_t ws_size,
                              hipStream_t stream) {
    const float* pred  = (const float*)d_in[0];
    const int* label   = (const int*)d_in[1];
    const int* factor  = (const int*)d_in[2];
    int n = in_sizes[1];
    float* out = (float*)d_out;

    char* ws = (char*)d_ws;
    Ctrl* c = (Ctrl*)ws;
    unsigned* keys = (unsigned*)(ws + 8192);
    float* nll = (float*)(ws + 8192 + (size_t)n * sizeof(unsigned));

    init_kernel<<<1, 256, 0, stream>>>((unsigned*)c, (int)(sizeof(Ctrl) / 4));
    row_kernel<<<2048, 256, 0, stream>>>(pred, label, keys, nll, c, n);
    scan_kernel<<<1, 256, 0, stream>>>(c, factor, 3, n);
    hist_kernel<<<1024, 256, 0, stream>>>(keys, c, n, 2);
    scan_kernel<<<1, 256, 0, stream>>>(c, factor, 2, n);
    hist_kernel<<<1024, 256, 0, stream>>>(keys, c, n, 1);
    scan_kernel<<<1, 256, 0, stream>>>(c, factor, 1, n);
    hist_kernel<<<1024, 256, 0, stream>>>(keys, c, n, 0);
    scan_kernel<<<1, 256, 0, stream>>>(c, factor, 0, n);
    reduce_kernel<<<2048, 256, 0, stream>>>(keys, label, nll, c, n);
    final_kernel<<<1, 64, 0, stream>>>(c, out);
}